// Round 1
// 262.624 us; speedup vs baseline: 1.0721x; 1.0721x over previous
//
#include <hip/hip_runtime.h>

typedef __bf16 bf16x8 __attribute__((ext_vector_type(8)));
typedef __bf16 bf16x4 __attribute__((ext_vector_type(4)));
typedef float f32x16 __attribute__((ext_vector_type(16)));

__device__ __forceinline__ unsigned short f2bf(float f) {
    union { float f; unsigned u; } v; v.f = f;
    unsigned r = (v.u + 0x7FFFu + ((v.u >> 16) & 1u)) >> 16;
    return (unsigned short)r;
}

// ---- weight conversion into MFMA fragment order (32x32x16 bf16) ----
// Frag mapping: lane l holds W[k0 + (l>>5)*8 + j][n0 + (l&31)], j=0..7.
// W1F index = ((g*8 + kb)*64 + l)*8 + j   (g: hidden col-group 0..31, kb: K-step 0..7, K pad 119->128)
// W2F index = ((gn*64 + kb)*64 + l)*8 + j (gn: out col-group 0..7, kb: K-step 0..63)
__global__ void conv_w(const float* __restrict__ W1, const float* __restrict__ W2,
                       unsigned short* __restrict__ W1F, unsigned short* __restrict__ W2F) {
    int b = blockIdx.x;
    if (b < 512) {
        int idx = b * 256 + threadIdx.x;                   // 131072
        int j = idx & 7, l = (idx >> 3) & 63, kb = (idx >> 9) & 7, g = idx >> 12;
        int k = kb * 16 + (l >> 5) * 8 + j;
        int h = g * 32 + (l & 31);
        float v = (k < 119) ? W1[(size_t)k * 1024 + h] : 0.0f;
        W1F[idx] = f2bf(v);
    } else {
        int idx = (b - 512) * 256 + threadIdx.x;           // 262144
        int j = idx & 7, l = (idx >> 3) & 63, kb = (idx >> 9) & 63, gn = idx >> 15;
        int k = kb * 16 + (l >> 5) * 8 + j;
        int n = gn * 32 + (l & 31);
        W2F[idx] = f2bf(W2[(size_t)k * 256 + n]);
    }
}

// ---- fused features + MLP ----
// 256 threads (4 waves), 64 rows/block, grid 2048. chunk = 128 hidden cols (8 chunks).
// Phase A (operand-SWAPPED): hacc = mfma(W1frag, Xfrag) => H^T tile: m in lane, h in regs.
//   -> H write is 8x ds_write_b64 of packed bf16x4 (h-contiguous), not 32x ds_write_b16.
// X fragments live in registers for the whole kernel (loaded from Xs once).
// Phase B: normal orientation (A = H rows from LDS, B = W2F frags prefetched ABOVE the
//   barrier with raw s_barrier + lgkmcnt(0)-only fences so global loads stay in flight).
__global__ __launch_bounds__(256, 2) void mlp_fused(
    const float* __restrict__ hole, const float* __restrict__ board,
    const float* __restrict__ b1, const float* __restrict__ b2,
    const unsigned short* __restrict__ W1F, const unsigned short* __restrict__ W2F,
    float* __restrict__ out)
{
    __shared__ unsigned short Xs[64][136];   // 17408 B; stride 136 shorts
    __shared__ unsigned short Hs[64][136];   // 17408 B

    const int tid  = threadIdx.x;
    const int w    = tid >> 6;
    const int lane = tid & 63;
    const int l32  = lane & 31;
    const int hi   = lane >> 5;      // 0/1 half-wave
    const long r0  = (long)blockIdx.x * 64;

    // ---------------- feature extraction: thread t < 64 handles row r0+t ----------------
    if (tid < 64) {
        const long r = r0 + tid;
        const float4* hp = (const float4*)(hole + r * 52);
        const float4* bp = (const float4*)(board + r * 52);
        unsigned long long hm = 0ull, bm = 0ull;
        #pragma unroll
        for (int i = 0; i < 13; ++i) {
            float4 h4 = hp[i], b4 = bp[i];
            int base = i * 4;
            hm |= ((unsigned long long)(h4.x > 0.5f)) << (base + 0);
            hm |= ((unsigned long long)(h4.y > 0.5f)) << (base + 1);
            hm |= ((unsigned long long)(h4.z > 0.5f)) << (base + 2);
            hm |= ((unsigned long long)(h4.w > 0.5f)) << (base + 3);
            bm |= ((unsigned long long)(b4.x > 0.5f)) << (base + 0);
            bm |= ((unsigned long long)(b4.y > 0.5f)) << (base + 1);
            bm |= ((unsigned long long)(b4.z > 0.5f)) << (base + 2);
            bm |= ((unsigned long long)(b4.w > 0.5f)) << (base + 3);
        }
        const unsigned long long am = hm | bm;
        const int bcount = __popcll(bm);
        const int hcount = __popcll(hm);

        int pairs_b = 0, pairs_a = 0;
        bool trips_b = false, trips_a = false;
        unsigned prb = 0, pra = 0;
        #pragma unroll
        for (int rr = 0; rr < 13; ++rr) {
            int cb = __popc((unsigned)((bm >> (4 * rr)) & 0xFull));
            int ca = __popc((unsigned)((am >> (4 * rr)) & 0xFull));
            pairs_b += (cb >= 2); trips_b = trips_b || (cb >= 3); prb |= (unsigned)(cb > 0) << rr;
            pairs_a += (ca >= 2); trips_a = trips_a || (ca >= 3); pra |= (unsigned)(ca > 0) << rr;
        }
        const unsigned long long SM = 0x1111111111111ull;
        int bscm = 0, ascm = 0;
        #pragma unroll
        for (int s = 0; s < 4; ++s) {
            int bs = __popcll(bm & (SM << s));
            int as = __popcll(am & (SM << s));
            bscm = bs > bscm ? bs : bscm;
            ascm = as > ascm ? as : ascm;
        }
        float strength = trips_b ? 0.8f : (pairs_b >= 2 ? 0.6f : (pairs_b >= 1 ? 0.4f : 0.2f));
        if (bcount == 0) strength = 0.0f;
        float flush_b = (bscm >= 3 && bcount > 0) ? 1.0f : 0.0f;
        bool sb = false;
        #pragma unroll
        for (int i = 0; i < 13; ++i) sb = sb || (__popc((prb >> i) & 0x1Fu) >= 3);
        float straight_b = (sb && bcount > 0) ? 1.0f : 0.0f;
        float gr0 = (bcount == 0) ? 1.0f : 0.0f;
        float gr3 = (bcount == 3) ? 1.0f : 0.0f;
        float gr4 = (bcount == 4) ? 1.0f : 0.0f;
        float gr5 = (bcount == 5) ? 1.0f : 0.0f;
        float valid = (hcount >= 2 && bcount >= 1) ? 1.0f : 0.0f;
        float flush_draw = (ascm == 4) ? 1.0f : 0.0f;
        float flush_outs = fmaxf(0.0f, 13.0f - (float)ascm) * (1.0f / 13.0f);
        int first = -1;
        #pragma unroll
        for (int i = 0; i < 13; ++i) {
            bool qq = (((pra >> i) & 1u) != 0u) && (__popc((pra >> i) & 0x1Fu) >= 4);
            if (qq && first < 0) first = i;
        }
        float straight_draw = (first >= 0) ? 1.0f : 0.0f;
        float straight_outs = 0.0f;
        if (first >= 0) {
            int c4 = __popc((pra >> first) & 0xFu);
            straight_outs = (c4 >= 4) ? 0.4f : 0.2f;
        }
        float total_outs = flush_draw * flush_outs * 9.0f + straight_draw * straight_outs * 8.0f;
        float remaining = 52.0f - (float)(hcount + bcount);
        float equity = 0.0f;
        if (remaining > 0.0f) equity = fminf(1.0f, total_outs / fmaxf(remaining, 1.0f));
        float hit_pair  = (pairs_a >= 1) ? 1.0f : 0.0f;
        float hit_trips = trips_a ? 1.0f : 0.0f;
        float hit_two   = (pairs_a >= 2) ? 1.0f : 0.0f;

        unsigned short* xrow = &Xs[tid][0];
        #pragma unroll
        for (int i = 0; i < 52; ++i) xrow[i]      = ((hm >> i) & 1ull) ? (unsigned short)0x3F80 : (unsigned short)0;
        #pragma unroll
        for (int i = 0; i < 52; ++i) xrow[52 + i] = ((bm >> i) & 1ull) ? (unsigned short)0x3F80 : (unsigned short)0;
        float feats[15] = { strength, flush_b, straight_b, gr0, gr3, gr4, gr5,
                            valid * flush_draw, valid * flush_outs, valid * straight_draw,
                            valid * straight_outs, valid * equity,
                            valid * hit_pair, valid * hit_trips, valid * hit_two };
        #pragma unroll
        for (int i = 0; i < 15; ++i) xrow[104 + i] = f2bf(feats[i]);
        #pragma unroll
        for (int i = 119; i < 128; ++i) xrow[i] = 0;
    }

    f32x16 acc[2][2];
    #pragma unroll
    for (int a = 0; a < 2; ++a)
        #pragma unroll
        for (int b = 0; b < 2; ++b)
            #pragma unroll
            for (int r = 0; r < 16; ++r) acc[a][b][r] = 0.0f;

    __syncthreads();

    // ---- X fragments -> registers, once. lane holds X[m=32*mi+l32][16*ks+8*hi+j] ----
    bf16x8 xf[2][8];
    #pragma unroll
    for (int mi = 0; mi < 2; ++mi)
        #pragma unroll
        for (int ks = 0; ks < 8; ++ks)
            xf[mi][ks] = *(const bf16x8*)&Xs[mi * 32 + l32][ks * 16 + hi * 8];

    f32x16 h0, h1;
    float4 bq[4];

    // ---- phase A, chunk 0 (swapped operands: hacc holds H^T tile, h in regs) ----
    {
        #pragma unroll
        for (int r = 0; r < 16; ++r) { h0[r] = 0.0f; h1[r] = 0.0f; }
        const unsigned short* w1p = W1F + ((size_t)(0 * 4 + w) * 8) * 512 + lane * 8;
        #pragma unroll
        for (int ks = 0; ks < 8; ++ks) {
            bf16x8 wfr = *(const bf16x8*)(w1p + ks * 512);
            h0 = __builtin_amdgcn_mfma_f32_32x32x16_bf16(wfr, xf[0][ks], h0, 0, 0, 0);
            h1 = __builtin_amdgcn_mfma_f32_32x32x16_bf16(wfr, xf[1][ks], h1, 0, 0, 0);
        }
        #pragma unroll
        for (int q = 0; q < 4; ++q) bq[q] = *(const float4*)&b1[0 * 128 + w * 32 + 8 * q + 4 * hi];
        // packed h-contiguous write: reg 4q+t <-> h = w*32 + 8q + 4hi + t
        #pragma unroll
        for (int q = 0; q < 4; ++q) {
            float f0 = fmaxf(h0[4 * q + 0] + bq[q].x, 0.0f);
            float f1 = fmaxf(h0[4 * q + 1] + bq[q].y, 0.0f);
            float f2 = fmaxf(h0[4 * q + 2] + bq[q].z, 0.0f);
            float f3 = fmaxf(h0[4 * q + 3] + bq[q].w, 0.0f);
            bf16x4 v = { (__bf16)f0, (__bf16)f1, (__bf16)f2, (__bf16)f3 };
            *(bf16x4*)&Hs[l32][w * 32 + 8 * q + 4 * hi] = v;
            f0 = fmaxf(h1[4 * q + 0] + bq[q].x, 0.0f);
            f1 = fmaxf(h1[4 * q + 1] + bq[q].y, 0.0f);
            f2 = fmaxf(h1[4 * q + 2] + bq[q].z, 0.0f);
            f3 = fmaxf(h1[4 * q + 3] + bq[q].w, 0.0f);
            bf16x4 v2 = { (__bf16)f0, (__bf16)f1, (__bf16)f2, (__bf16)f3 };
            *(bf16x4*)&Hs[32 + l32][w * 32 + 8 * q + 4 * hi] = v2;
        }
    }

    for (int c = 1; c < 8; ++c) {
        // prefetch W2F frags for chunk c-1: issued BEFORE the barrier, stay in flight across it
        bf16x8 wf20[8], wf21[8];
        {
            const unsigned short* w2p0 = W2F + ((size_t)(2 * w + 0) * 64 + (c - 1) * 8) * 512 + lane * 8;
            const unsigned short* w2p1 = W2F + ((size_t)(2 * w + 1) * 64 + (c - 1) * 8) * 512 + lane * 8;
            #pragma unroll
            for (int ks = 0; ks < 8; ++ks) {
                wf20[ks] = *(const bf16x8*)(w2p0 + ks * 512);
                wf21[ks] = *(const bf16x8*)(w2p1 + ks * 512);
            }
        }
        asm volatile("s_waitcnt lgkmcnt(0)" ::: "memory");   // my Hs(c-1) writes performed
        __builtin_amdgcn_s_barrier();                        // Hs(c-1) visible; vmcnt NOT drained

        // ---- phase B, chunk c-1 (Hs reads + prefetched W2F) ----
        #pragma unroll
        for (int ks = 0; ks < 8; ++ks) {
            bf16x8 a0 = *(const bf16x8*)&Hs[l32][ks * 16 + hi * 8];
            bf16x8 a1 = *(const bf16x8*)&Hs[32 + l32][ks * 16 + hi * 8];
            acc[0][0] = __builtin_amdgcn_mfma_f32_32x32x16_bf16(a0, wf20[ks], acc[0][0], 0, 0, 0);
            acc[0][1] = __builtin_amdgcn_mfma_f32_32x32x16_bf16(a0, wf21[ks], acc[0][1], 0, 0, 0);
            acc[1][0] = __builtin_amdgcn_mfma_f32_32x32x16_bf16(a1, wf20[ks], acc[1][0], 0, 0, 0);
            acc[1][1] = __builtin_amdgcn_mfma_f32_32x32x16_bf16(a1, wf21[ks], acc[1][1], 0, 0, 0);
        }

        // ---- phase A, chunk c (pure-register MFMA stream: X in regs, W1F from global) ----
        #pragma unroll
        for (int r = 0; r < 16; ++r) { h0[r] = 0.0f; h1[r] = 0.0f; }
        const unsigned short* w1p = W1F + ((size_t)(c * 4 + w) * 8) * 512 + lane * 8;
        #pragma unroll
        for (int ks = 0; ks < 8; ++ks) {
            bf16x8 wfr = *(const bf16x8*)(w1p + ks * 512);
            h0 = __builtin_amdgcn_mfma_f32_32x32x16_bf16(wfr, xf[0][ks], h0, 0, 0, 0);
            h1 = __builtin_amdgcn_mfma_f32_32x32x16_bf16(wfr, xf[1][ks], h1, 0, 0, 0);
        }
        #pragma unroll
        for (int q = 0; q < 4; ++q) bq[q] = *(const float4*)&b1[c * 128 + w * 32 + 8 * q + 4 * hi];

        asm volatile("s_waitcnt lgkmcnt(0)" ::: "memory");   // my Hs(c-1) reads performed
        __builtin_amdgcn_s_barrier();                        // all waves done reading Hs(c-1)

        // ---- write Hs chunk c (packed b64, h-contiguous) ----
        #pragma unroll
        for (int q = 0; q < 4; ++q) {
            float f0 = fmaxf(h0[4 * q + 0] + bq[q].x, 0.0f);
            float f1 = fmaxf(h0[4 * q + 1] + bq[q].y, 0.0f);
            float f2 = fmaxf(h0[4 * q + 2] + bq[q].z, 0.0f);
            float f3 = fmaxf(h0[4 * q + 3] + bq[q].w, 0.0f);
            bf16x4 v = { (__bf16)f0, (__bf16)f1, (__bf16)f2, (__bf16)f3 };
            *(bf16x4*)&Hs[l32][w * 32 + 8 * q + 4 * hi] = v;
            f0 = fmaxf(h1[4 * q + 0] + bq[q].x, 0.0f);
            f1 = fmaxf(h1[4 * q + 1] + bq[q].y, 0.0f);
            f2 = fmaxf(h1[4 * q + 2] + bq[q].z, 0.0f);
            f3 = fmaxf(h1[4 * q + 3] + bq[q].w, 0.0f);
            bf16x4 v2 = { (__bf16)f0, (__bf16)f1, (__bf16)f2, (__bf16)f3 };
            *(bf16x4*)&Hs[32 + l32][w * 32 + 8 * q + 4 * hi] = v2;
        }
    }

    // ---- phase B, chunk 7 ----
    {
        bf16x8 wf20[8], wf21[8];
        const unsigned short* w2p0 = W2F + ((size_t)(2 * w + 0) * 64 + 7 * 8) * 512 + lane * 8;
        const unsigned short* w2p1 = W2F + ((size_t)(2 * w + 1) * 64 + 7 * 8) * 512 + lane * 8;
        #pragma unroll
        for (int ks = 0; ks < 8; ++ks) {
            wf20[ks] = *(const bf16x8*)(w2p0 + ks * 512);
            wf21[ks] = *(const bf16x8*)(w2p1 + ks * 512);
        }
        asm volatile("s_waitcnt lgkmcnt(0)" ::: "memory");
        __builtin_amdgcn_s_barrier();
        #pragma unroll
        for (int ks = 0; ks < 8; ++ks) {
            bf16x8 a0 = *(const bf16x8*)&Hs[l32][ks * 16 + hi * 8];
            bf16x8 a1 = *(const bf16x8*)&Hs[32 + l32][ks * 16 + hi * 8];
            acc[0][0] = __builtin_amdgcn_mfma_f32_32x32x16_bf16(a0, wf20[ks], acc[0][0], 0, 0, 0);
            acc[0][1] = __builtin_amdgcn_mfma_f32_32x32x16_bf16(a0, wf21[ks], acc[0][1], 0, 0, 0);
            acc[1][0] = __builtin_amdgcn_mfma_f32_32x32x16_bf16(a1, wf20[ks], acc[1][0], 0, 0, 0);
            acc[1][1] = __builtin_amdgcn_mfma_f32_32x32x16_bf16(a1, wf21[ks], acc[1][1], 0, 0, 0);
        }
    }

    // ---- epilogue: + b2, store f32 ----
    #pragma unroll
    for (int ni = 0; ni < 2; ++ni) {
        const int col = (2 * w + ni) * 32 + l32;
        const float bb = b2[col];
        #pragma unroll
        for (int mi = 0; mi < 2; ++mi) {
            #pragma unroll
            for (int r = 0; r < 16; ++r) {
                const long row = r0 + mi * 32 + (r & 3) + 8 * (r >> 2) + 4 * hi;
                out[row * 256 + col] = acc[mi][ni][r] + bb;
            }
        }
    }
}

extern "C" void kernel_launch(void* const* d_in, const int* in_sizes, int n_in,
                              void* d_out, int out_size, void* d_ws, size_t ws_size,
                              hipStream_t stream) {
    (void)in_sizes; (void)n_in; (void)out_size; (void)ws_size;
    const float* hole  = (const float*)d_in[0];
    const float* board = (const float*)d_in[1];
    const float* W1    = (const float*)d_in[2];
    const float* b1    = (const float*)d_in[3];
    const float* W2    = (const float*)d_in[4];
    const float* b2    = (const float*)d_in[5];
    float* out = (float*)d_out;

    unsigned short* W1F = (unsigned short*)d_ws;            // 131072 bf16 = 256 KB
    unsigned short* W2F = W1F + 131072;                     // 262144 bf16 = 512 KB

    conv_w<<<1536, 256, 0, stream>>>(W1, W2, W1F, W2F);
    mlp_fused<<<131072 / 64, 256, 0, stream>>>(hole, board, b1, b2, W1F, W2F, out);
}

// Round 2
// 258.279 us; speedup vs baseline: 1.0901x; 1.0168x over previous
//
#include <hip/hip_runtime.h>

typedef __bf16 bf16x8 __attribute__((ext_vector_type(8)));
typedef __bf16 bf16x4 __attribute__((ext_vector_type(4)));
typedef float f32x16 __attribute__((ext_vector_type(16)));

__device__ __forceinline__ unsigned short f2bf(float f) {
    union { float f; unsigned u; } v; v.f = f;
    unsigned r = (v.u + 0x7FFFu + ((v.u >> 16) & 1u)) >> 16;
    return (unsigned short)r;
}

// ---- weight conversion into MFMA fragment order (32x32x16 bf16) ----
// Frag mapping: lane l holds W[k0 + (l>>5)*8 + j][n0 + (l&31)], j=0..7.
// W1F index = ((g*8 + kb)*64 + l)*8 + j   (g: hidden col-group 0..31, kb: K-step 0..7, K pad 119->128)
// W2F index = ((gn*64 + kb)*64 + l)*8 + j (gn: out col-group 0..7, kb: K-step 0..63)
__global__ void conv_w(const float* __restrict__ W1, const float* __restrict__ W2,
                       unsigned short* __restrict__ W1F, unsigned short* __restrict__ W2F) {
    int b = blockIdx.x;
    if (b < 512) {
        int idx = b * 256 + threadIdx.x;                   // 131072
        int j = idx & 7, l = (idx >> 3) & 63, kb = (idx >> 9) & 7, g = idx >> 12;
        int k = kb * 16 + (l >> 5) * 8 + j;
        int h = g * 32 + (l & 31);
        float v = (k < 119) ? W1[(size_t)k * 1024 + h] : 0.0f;
        W1F[idx] = f2bf(v);
    } else {
        int idx = (b - 512) * 256 + threadIdx.x;           // 262144
        int j = idx & 7, l = (idx >> 3) & 63, kb = (idx >> 9) & 63, gn = idx >> 15;
        int k = kb * 16 + (l >> 5) * 8 + j;
        int n = gn * 32 + (l & 31);
        W2F[idx] = f2bf(W2[(size_t)k * 256 + n]);
    }
}

// ---- fused features + MLP ----
// 256 threads (4 waves), 64 rows/block, grid 2048. chunk = 128 hidden cols (8 chunks).
// LDS layout (T2): element (r,c) at short-index r*128 + (c ^ ((r&7)<<3)) -- XOR swizzle makes
//   both the row-varying ds_write_b64 (H store) and ds_read_b128 (A-frag loads) bank-conflict-free.
// Pipeline: double-buffered Hs -> ONE barrier per chunk. Phase B(c) and phase A(c+1) share a
//   barrier-free region so W1F L2 latency hides under phase-B MFMAs. W2F(c+1) prefetch issues
//   after its last use and stays in flight across the barrier (vmcnt never drained at barriers).
__global__ __launch_bounds__(256, 2) void mlp_fused(
    const float* __restrict__ hole, const float* __restrict__ board,
    const float* __restrict__ b1, const float* __restrict__ b2,
    const unsigned short* __restrict__ W1F, const unsigned short* __restrict__ W2F,
    float* __restrict__ out)
{
    __shared__ unsigned short Xs[64 * 128];       // 16 KB, swizzled
    __shared__ unsigned short Hs[2][64 * 128];    // 2 x 16 KB, swizzled

    const int tid  = threadIdx.x;
    const int w    = tid >> 6;
    const int lane = tid & 63;
    const int l32  = lane & 31;
    const int hi   = lane >> 5;      // 0/1 half-wave
    const long r0  = (long)blockIdx.x * 64;

    // ---------------- feature extraction: thread t < 64 handles row r0+t ----------------
    if (tid < 64) {
        const long r = r0 + tid;
        const float4* hp = (const float4*)(hole + r * 52);
        const float4* bp = (const float4*)(board + r * 52);
        unsigned long long hm = 0ull, bm = 0ull;
        #pragma unroll
        for (int i = 0; i < 13; ++i) {
            float4 h4 = hp[i], b4 = bp[i];
            int base = i * 4;
            hm |= ((unsigned long long)(h4.x > 0.5f)) << (base + 0);
            hm |= ((unsigned long long)(h4.y > 0.5f)) << (base + 1);
            hm |= ((unsigned long long)(h4.z > 0.5f)) << (base + 2);
            hm |= ((unsigned long long)(h4.w > 0.5f)) << (base + 3);
            bm |= ((unsigned long long)(b4.x > 0.5f)) << (base + 0);
            bm |= ((unsigned long long)(b4.y > 0.5f)) << (base + 1);
            bm |= ((unsigned long long)(b4.z > 0.5f)) << (base + 2);
            bm |= ((unsigned long long)(b4.w > 0.5f)) << (base + 3);
        }
        const unsigned long long am = hm | bm;
        const int bcount = __popcll(bm);
        const int hcount = __popcll(hm);

        int pairs_b = 0, pairs_a = 0;
        bool trips_b = false, trips_a = false;
        unsigned prb = 0, pra = 0;
        #pragma unroll
        for (int rr = 0; rr < 13; ++rr) {
            int cb = __popc((unsigned)((bm >> (4 * rr)) & 0xFull));
            int ca = __popc((unsigned)((am >> (4 * rr)) & 0xFull));
            pairs_b += (cb >= 2); trips_b = trips_b || (cb >= 3); prb |= (unsigned)(cb > 0) << rr;
            pairs_a += (ca >= 2); trips_a = trips_a || (ca >= 3); pra |= (unsigned)(ca > 0) << rr;
        }
        const unsigned long long SM = 0x1111111111111ull;
        int bscm = 0, ascm = 0;
        #pragma unroll
        for (int s = 0; s < 4; ++s) {
            int bs = __popcll(bm & (SM << s));
            int as = __popcll(am & (SM << s));
            bscm = bs > bscm ? bs : bscm;
            ascm = as > ascm ? as : ascm;
        }
        float strength = trips_b ? 0.8f : (pairs_b >= 2 ? 0.6f : (pairs_b >= 1 ? 0.4f : 0.2f));
        if (bcount == 0) strength = 0.0f;
        float flush_b = (bscm >= 3 && bcount > 0) ? 1.0f : 0.0f;
        bool sb = false;
        #pragma unroll
        for (int i = 0; i < 13; ++i) sb = sb || (__popc((prb >> i) & 0x1Fu) >= 3);
        float straight_b = (sb && bcount > 0) ? 1.0f : 0.0f;
        float gr0 = (bcount == 0) ? 1.0f : 0.0f;
        float gr3 = (bcount == 3) ? 1.0f : 0.0f;
        float gr4 = (bcount == 4) ? 1.0f : 0.0f;
        float gr5 = (bcount == 5) ? 1.0f : 0.0f;
        float valid = (hcount >= 2 && bcount >= 1) ? 1.0f : 0.0f;
        float flush_draw = (ascm == 4) ? 1.0f : 0.0f;
        float flush_outs = fmaxf(0.0f, 13.0f - (float)ascm) * (1.0f / 13.0f);
        int first = -1;
        #pragma unroll
        for (int i = 0; i < 13; ++i) {
            bool qq = (((pra >> i) & 1u) != 0u) && (__popc((pra >> i) & 0x1Fu) >= 4);
            if (qq && first < 0) first = i;
        }
        float straight_draw = (first >= 0) ? 1.0f : 0.0f;
        float straight_outs = 0.0f;
        if (first >= 0) {
            int c4 = __popc((pra >> first) & 0xFu);
            straight_outs = (c4 >= 4) ? 0.4f : 0.2f;
        }
        float total_outs = flush_draw * flush_outs * 9.0f + straight_draw * straight_outs * 8.0f;
        float remaining = 52.0f - (float)(hcount + bcount);
        float equity = 0.0f;
        if (remaining > 0.0f) equity = fminf(1.0f, total_outs / fmaxf(remaining, 1.0f));
        float hit_pair  = (pairs_a >= 1) ? 1.0f : 0.0f;
        float hit_trips = trips_a ? 1.0f : 0.0f;
        float hit_two   = (pairs_a >= 2) ? 1.0f : 0.0f;

        unsigned short* xrow = &Xs[tid * 128];
        const int fsw = (tid & 7) << 3;          // swizzle constant for this row
        #pragma unroll
        for (int i = 0; i < 52; ++i) xrow[i ^ fsw]        = ((hm >> i) & 1ull) ? (unsigned short)0x3F80 : (unsigned short)0;
        #pragma unroll
        for (int i = 0; i < 52; ++i) xrow[(52 + i) ^ fsw] = ((bm >> i) & 1ull) ? (unsigned short)0x3F80 : (unsigned short)0;
        float feats[15] = { strength, flush_b, straight_b, gr0, gr3, gr4, gr5,
                            valid * flush_draw, valid * flush_outs, valid * straight_draw,
                            valid * straight_outs, valid * equity,
                            valid * hit_pair, valid * hit_trips, valid * hit_two };
        #pragma unroll
        for (int i = 0; i < 15; ++i) xrow[(104 + i) ^ fsw] = f2bf(feats[i]);
        #pragma unroll
        for (int i = 119; i < 128; ++i) xrow[i ^ fsw] = 0;
    }

    f32x16 acc[2][2];
    #pragma unroll
    for (int a = 0; a < 2; ++a)
        #pragma unroll
        for (int b = 0; b < 2; ++b)
            #pragma unroll
            for (int r = 0; r < 16; ++r) acc[a][b][r] = 0.0f;

    __syncthreads();

    const int sw = (l32 & 7) << 3;               // rows l32 and 32+l32 share (r&7)
    unsigned short* const x0 = &Xs[l32 * 128];
    unsigned short* const x1 = &Xs[(32 + l32) * 128];

    // ---- X fragments -> registers, once ----
    bf16x8 xf[2][8];
    #pragma unroll
    for (int ks = 0; ks < 8; ++ks) {
        const int off = (ks * 16 + hi * 8) ^ sw;
        xf[0][ks] = *(const bf16x8*)&x0[off];
        xf[1][ks] = *(const bf16x8*)&x1[off];
    }

    f32x16 h0, h1;
    bf16x8 wf1[8];
    bf16x8 wf20[8], wf21[8];
    float4 bq[4];

    // ---- prologue: phase A chunk 0 -> Hs[0]; W2F(0) prefetch; barrier ----
    {
        const unsigned short* w1p = W1F + ((size_t)(0 * 4 + w) * 8) * 512 + lane * 8;
        #pragma unroll
        for (int ks = 0; ks < 8; ++ks) wf1[ks] = *(const bf16x8*)(w1p + ks * 512);
        #pragma unroll
        for (int q = 0; q < 4; ++q) bq[q] = *(const float4*)&b1[0 * 128 + w * 32 + 8 * q + 4 * hi];
        #pragma unroll
        for (int r = 0; r < 16; ++r) { h0[r] = 0.0f; h1[r] = 0.0f; }
        #pragma unroll
        for (int ks = 0; ks < 8; ++ks) {
            h0 = __builtin_amdgcn_mfma_f32_32x32x16_bf16(wf1[ks], xf[0][ks], h0, 0, 0, 0);
            h1 = __builtin_amdgcn_mfma_f32_32x32x16_bf16(wf1[ks], xf[1][ks], h1, 0, 0, 0);
        }
        unsigned short* hr0 = &Hs[0][l32 * 128];
        unsigned short* hr1 = &Hs[0][(32 + l32) * 128];
        #pragma unroll
        for (int q = 0; q < 4; ++q) {
            const int cb = (w * 32 + 8 * q + 4 * hi) ^ sw;
            float f0 = fmaxf(h0[4 * q + 0] + bq[q].x, 0.0f);
            float f1 = fmaxf(h0[4 * q + 1] + bq[q].y, 0.0f);
            float f2 = fmaxf(h0[4 * q + 2] + bq[q].z, 0.0f);
            float f3 = fmaxf(h0[4 * q + 3] + bq[q].w, 0.0f);
            bf16x4 v = { (__bf16)f0, (__bf16)f1, (__bf16)f2, (__bf16)f3 };
            *(bf16x4*)&hr0[cb] = v;
            f0 = fmaxf(h1[4 * q + 0] + bq[q].x, 0.0f);
            f1 = fmaxf(h1[4 * q + 1] + bq[q].y, 0.0f);
            f2 = fmaxf(h1[4 * q + 2] + bq[q].z, 0.0f);
            f3 = fmaxf(h1[4 * q + 3] + bq[q].w, 0.0f);
            bf16x4 v2 = { (__bf16)f0, (__bf16)f1, (__bf16)f2, (__bf16)f3 };
            *(bf16x4*)&hr1[cb] = v2;
        }
        // W2F(0) prefetch: issued before barrier, in flight across it
        const unsigned short* w2p0 = W2F + ((size_t)(2 * w + 0) * 64 + 0 * 8) * 512 + lane * 8;
        const unsigned short* w2p1 = W2F + ((size_t)(2 * w + 1) * 64 + 0 * 8) * 512 + lane * 8;
        #pragma unroll
        for (int ks = 0; ks < 8; ++ks) {
            wf20[ks] = *(const bf16x8*)(w2p0 + ks * 512);
            wf21[ks] = *(const bf16x8*)(w2p1 + ks * 512);
        }
        asm volatile("s_waitcnt lgkmcnt(0)" ::: "memory");
        __builtin_amdgcn_s_barrier();
    }

    // ---- main loop: ONE barrier per chunk ----
    for (int c = 0; c < 8; ++c) {
        const unsigned short* hr0 = &Hs[c & 1][l32 * 128];
        const unsigned short* hr1 = &Hs[c & 1][(32 + l32) * 128];

        if (c < 7) {
            // issue W1F(c+1) + bias loads at region top: latency hides under phase-B MFMAs
            const unsigned short* w1p = W1F + ((size_t)((c + 1) * 4 + w) * 8) * 512 + lane * 8;
            #pragma unroll
            for (int ks = 0; ks < 8; ++ks) wf1[ks] = *(const bf16x8*)(w1p + ks * 512);
            #pragma unroll
            for (int q = 0; q < 4; ++q) bq[q] = *(const float4*)&b1[(c + 1) * 128 + w * 32 + 8 * q + 4 * hi];
        }

        // ---- phase B, chunk c ----
        #pragma unroll
        for (int ks = 0; ks < 8; ++ks) {
            const int off = (ks * 16 + hi * 8) ^ sw;
            bf16x8 a0 = *(const bf16x8*)&hr0[off];
            bf16x8 a1 = *(const bf16x8*)&hr1[off];
            acc[0][0] = __builtin_amdgcn_mfma_f32_32x32x16_bf16(a0, wf20[ks], acc[0][0], 0, 0, 0);
            acc[0][1] = __builtin_amdgcn_mfma_f32_32x32x16_bf16(a0, wf21[ks], acc[0][1], 0, 0, 0);
            acc[1][0] = __builtin_amdgcn_mfma_f32_32x32x16_bf16(a1, wf20[ks], acc[1][0], 0, 0, 0);
            acc[1][1] = __builtin_amdgcn_mfma_f32_32x32x16_bf16(a1, wf21[ks], acc[1][1], 0, 0, 0);
        }

        if (c < 7) {
            // W2F(c+1) prefetch: after last wf2 use, before barrier -> in flight across it
            const unsigned short* w2p0 = W2F + ((size_t)(2 * w + 0) * 64 + (c + 1) * 8) * 512 + lane * 8;
            const unsigned short* w2p1 = W2F + ((size_t)(2 * w + 1) * 64 + (c + 1) * 8) * 512 + lane * 8;
            #pragma unroll
            for (int ks = 0; ks < 8; ++ks) {
                wf20[ks] = *(const bf16x8*)(w2p0 + ks * 512);
                wf21[ks] = *(const bf16x8*)(w2p1 + ks * 512);
            }

            // ---- phase A, chunk c+1 (pure-register MFMA stream) ----
            #pragma unroll
            for (int r = 0; r < 16; ++r) { h0[r] = 0.0f; h1[r] = 0.0f; }
            #pragma unroll
            for (int ks = 0; ks < 8; ++ks) {
                h0 = __builtin_amdgcn_mfma_f32_32x32x16_bf16(wf1[ks], xf[0][ks], h0, 0, 0, 0);
                h1 = __builtin_amdgcn_mfma_f32_32x32x16_bf16(wf1[ks], xf[1][ks], h1, 0, 0, 0);
            }

            // ---- write H(c+1) -> Hs[(c+1)&1] ----
            // anti-dep vs other waves' reads of this buffer (chunk c-1) is ordered by the
            // barrier at the end of iteration c-1.
            unsigned short* hw0 = &Hs[(c + 1) & 1][l32 * 128];
            unsigned short* hw1 = &Hs[(c + 1) & 1][(32 + l32) * 128];
            #pragma unroll
            for (int q = 0; q < 4; ++q) {
                const int cb = (w * 32 + 8 * q + 4 * hi) ^ sw;
                float f0 = fmaxf(h0[4 * q + 0] + bq[q].x, 0.0f);
                float f1 = fmaxf(h0[4 * q + 1] + bq[q].y, 0.0f);
                float f2 = fmaxf(h0[4 * q + 2] + bq[q].z, 0.0f);
                float f3 = fmaxf(h0[4 * q + 3] + bq[q].w, 0.0f);
                bf16x4 v = { (__bf16)f0, (__bf16)f1, (__bf16)f2, (__bf16)f3 };
                *(bf16x4*)&hw0[cb] = v;
                f0 = fmaxf(h1[4 * q + 0] + bq[q].x, 0.0f);
                f1 = fmaxf(h1[4 * q + 1] + bq[q].y, 0.0f);
                f2 = fmaxf(h1[4 * q + 2] + bq[q].z, 0.0f);
                f3 = fmaxf(h1[4 * q + 3] + bq[q].w, 0.0f);
                bf16x4 v2 = { (__bf16)f0, (__bf16)f1, (__bf16)f2, (__bf16)f3 };
                *(bf16x4*)&hw1[cb] = v2;
            }

            asm volatile("s_waitcnt lgkmcnt(0)" ::: "memory");   // my ds reads+writes retired
            __builtin_amdgcn_s_barrier();                        // vmcnt NOT drained
        }
    }

    // ---- epilogue: + b2, store f32 ----
    #pragma unroll
    for (int ni = 0; ni < 2; ++ni) {
        const int col = (2 * w + ni) * 32 + l32;
        const float bb = b2[col];
        #pragma unroll
        for (int mi = 0; mi < 2; ++mi) {
            #pragma unroll
            for (int r = 0; r < 16; ++r) {
                const long row = r0 + mi * 32 + (r & 3) + 8 * (r >> 2) + 4 * hi;
                out[row * 256 + col] = acc[mi][ni][r] + bb;
            }
        }
    }
}

extern "C" void kernel_launch(void* const* d_in, const int* in_sizes, int n_in,
                              void* d_out, int out_size, void* d_ws, size_t ws_size,
                              hipStream_t stream) {
    (void)in_sizes; (void)n_in; (void)out_size; (void)ws_size;
    const float* hole  = (const float*)d_in[0];
    const float* board = (const float*)d_in[1];
    const float* W1    = (const float*)d_in[2];
    const float* b1    = (const float*)d_in[3];
    const float* W2    = (const float*)d_in[4];
    const float* b2    = (const float*)d_in[5];
    float* out = (float*)d_out;

    unsigned short* W1F = (unsigned short*)d_ws;            // 131072 bf16 = 256 KB
    unsigned short* W2F = W1F + 131072;                     // 262144 bf16 = 512 KB

    conv_w<<<1536, 256, 0, stream>>>(W1, W2, W1F, W2F);
    mlp_fused<<<131072 / 64, 256, 0, stream>>>(hole, board, b1, b2, W1F, W2F, out);
}